// Round 1
// baseline (531.993 us; speedup 1.0000x reference)
//
#include <hip/hip_runtime.h>

#define N_NODES 50000
#define E0      800000
#define ETOT    850000

// ---------------- CSR build ----------------

__global__ __launch_bounds__(256) void k_deg(const int* __restrict__ ei, int* __restrict__ deg) {
    int e = blockIdx.x * 256 + threadIdx.x;
    if (e >= ETOT) return;
    int dst = (e < E0) ? ei[E0 + e] : (e - E0);
    atomicAdd(&deg[dst], 1);
}

__global__ __launch_bounds__(256) void k_scan1(const int* __restrict__ deg, int* __restrict__ offs,
                                               int* __restrict__ bsum) {
    __shared__ int buf[256];
    int tid = threadIdx.x;
    int i = blockIdx.x * 256 + tid;
    int v = (i < N_NODES) ? deg[i] : 0;
    buf[tid] = v;
    __syncthreads();
    for (int off = 1; off < 256; off <<= 1) {
        int t = (tid >= off) ? buf[tid - off] : 0;
        __syncthreads();
        buf[tid] += t;
        __syncthreads();
    }
    if (i < N_NODES) offs[i + 1] = buf[tid];     // block-local inclusive
    if (tid == 255) bsum[blockIdx.x] = buf[255];
}

__global__ __launch_bounds__(256) void k_scan2(int* __restrict__ bsum, int nb) {
    __shared__ int buf[256];
    int tid = threadIdx.x;
    int v = (tid < nb) ? bsum[tid] : 0;
    buf[tid] = v;
    __syncthreads();
    for (int off = 1; off < 256; off <<= 1) {
        int t = (tid >= off) ? buf[tid - off] : 0;
        __syncthreads();
        buf[tid] += t;
        __syncthreads();
    }
    if (tid < nb) bsum[tid] = buf[tid] - v;      // exclusive
}

__global__ __launch_bounds__(256) void k_scan3(int* __restrict__ offs, const int* __restrict__ bsum) {
    int tid = threadIdx.x;
    int i = blockIdx.x * 256 + tid;
    if (i < N_NODES) offs[i + 1] += bsum[blockIdx.x];
    if (i == 0) offs[0] = 0;
}

__global__ __launch_bounds__(256) void k_copy(const int* __restrict__ offs, int* __restrict__ cursor) {
    int i = blockIdx.x * 256 + threadIdx.x;
    if (i < N_NODES) cursor[i] = offs[i];
}

__global__ __launch_bounds__(256) void k_scatter(const int* __restrict__ ei, int* __restrict__ cursor,
                                                 int* __restrict__ esrc) {
    int e = blockIdx.x * 256 + threadIdx.x;
    if (e >= ETOT) return;
    int src, dst;
    if (e < E0) { src = ei[e]; dst = ei[E0 + e]; }
    else        { src = e - E0; dst = src; }
    int pos = atomicAdd(&cursor[dst], 1);
    esrc[pos] = src;
}

// ---------------- fp32 tiled GEMM: C[M,Nn] = A[M,K] @ B[K,Nn] ----------------

__global__ __launch_bounds__(256) void k_gemm(const float* __restrict__ A, const float* __restrict__ B,
                                              float* __restrict__ C, int M, int Nn, int K) {
    __shared__ float As[16][65];
    __shared__ float Bs[16][64];
    int tid = threadIdx.x;
    int tx = tid & 15, ty = tid >> 4;
    int bm = blockIdx.x * 64, bn = blockIdx.y * 64;
    float acc[4][4] = {};
    for (int kt = 0; kt < K; kt += 16) {
        {
            int r = tid >> 2, c = (tid & 3) << 2;
            int grow = bm + r;
            float4 v = make_float4(0.f, 0.f, 0.f, 0.f);
            if (grow < M) v = *(const float4*)(A + (size_t)grow * K + kt + c);
            As[c + 0][r] = v.x; As[c + 1][r] = v.y; As[c + 2][r] = v.z; As[c + 3][r] = v.w;
        }
        {
            int r = tid >> 4, c = (tid & 15) << 2;
            float4 v = *(const float4*)(B + (size_t)(kt + r) * Nn + bn + c);
            *(float4*)&Bs[r][c] = v;
        }
        __syncthreads();
#pragma unroll
        for (int k = 0; k < 16; ++k) {
            float a[4], b[4];
#pragma unroll
            for (int i = 0; i < 4; ++i) a[i] = As[k][ty * 4 + i];
#pragma unroll
            for (int j = 0; j < 4; ++j) b[j] = Bs[k][tx * 4 + j];
#pragma unroll
            for (int i = 0; i < 4; ++i)
#pragma unroll
                for (int j = 0; j < 4; ++j) acc[i][j] += a[i] * b[j];
        }
        __syncthreads();
    }
#pragma unroll
    for (int i = 0; i < 4; ++i) {
        int row = bm + ty * 4 + i;
        if (row < M) {
            float4 v = make_float4(acc[i][0], acc[i][1], acc[i][2], acc[i][3]);
            *(float4*)(C + (size_t)row * Nn + bn + tx * 4) = v;
        }
    }
}

// ---------------- per-node kernels (one wave / node) ----------------

__global__ __launch_bounds__(256) void k_alpha(const float* __restrict__ h, const float* __restrict__ a_src,
                                               const float* __restrict__ a_dst, float* __restrict__ as,
                                               float* __restrict__ ad, int F) {
    int gw = (blockIdx.x * 256 + threadIdx.x) >> 6;
    int lane = threadIdx.x & 63;
    if (gw >= N_NODES) return;
    const float* row = h + (size_t)gw * F;
    float s = 0.f, d = 0.f;
    for (int f = lane; f < F; f += 64) {
        float v = row[f];
        s += v * a_src[f];
        d += v * a_dst[f];
    }
    for (int o = 32; o; o >>= 1) { s += __shfl_down(s, o); d += __shfl_down(d, o); }
    if (lane == 0) { as[gw] = s; ad[gw] = d; }
}

__global__ __launch_bounds__(256) void k_coef(const int* __restrict__ offs, const int* __restrict__ esrc,
                                              const float* __restrict__ as, const float* __restrict__ ad,
                                              float* __restrict__ coef) {
    int gw = (blockIdx.x * 256 + threadIdx.x) >> 6;
    int lane = threadIdx.x & 63;
    if (gw >= N_NODES) return;
    int s0 = offs[gw], s1 = offs[gw + 1];
    float adi = ad[gw];
    float m = -1e30f;
    for (int k = s0 + lane; k < s1; k += 64) {
        float ev = as[esrc[k]] + adi;
        ev = ev > 0.f ? ev : 0.2f * ev;
        m = fmaxf(m, ev);
    }
    for (int o = 32; o; o >>= 1) m = fmaxf(m, __shfl_xor(m, o));
    float sum = 0.f;
    for (int k = s0 + lane; k < s1; k += 64) {
        float ev = as[esrc[k]] + adi;
        ev = ev > 0.f ? ev : 0.2f * ev;
        sum += __expf(ev - m);
    }
    for (int o = 32; o; o >>= 1) sum += __shfl_xor(sum, o);
    float inv = 1.f / sum;
    for (int k = s0 + lane; k < s1; k += 64) {
        float ev = as[esrc[k]] + adi;
        ev = ev > 0.f ? ev : 0.2f * ev;
        coef[k] = __expf(ev - m) * inv;
    }
}

template <int F, bool RELU>
__global__ __launch_bounds__(256) void k_aggregate(const int* __restrict__ offs, const int* __restrict__ esrc,
                                                   const float* __restrict__ coef, const float* __restrict__ h,
                                                   const float* __restrict__ bias, float* __restrict__ out) {
    constexpr int V = F / 64;
    int gw = (blockIdx.x * 256 + threadIdx.x) >> 6;
    int lane = threadIdx.x & 63;
    if (gw >= N_NODES) return;
    int s0 = offs[gw], s1 = offs[gw + 1];
    float acc[V] = {};
    for (int k = s0; k < s1; ++k) {
        float c = coef[k];
        const float* row = h + (size_t)esrc[k] * F + lane * V;
        if constexpr (V == 4) {
            float4 v = *(const float4*)row;
            acc[0] += c * v.x; acc[1] += c * v.y; acc[2] += c * v.z; acc[3] += c * v.w;
        } else {
            float2 v = *(const float2*)row;
            acc[0] += c * v.x; acc[1] += c * v.y;
        }
    }
    float* o = out + (size_t)gw * F + lane * V;
    if constexpr (V == 4) {
        float4 r;
        r.x = acc[0] + bias[lane * 4 + 0];
        r.y = acc[1] + bias[lane * 4 + 1];
        r.z = acc[2] + bias[lane * 4 + 2];
        r.w = acc[3] + bias[lane * 4 + 3];
        if (RELU) { r.x = fmaxf(r.x, 0.f); r.y = fmaxf(r.y, 0.f); r.z = fmaxf(r.z, 0.f); r.w = fmaxf(r.w, 0.f); }
        *(float4*)o = r;
    } else {
        float2 r;
        r.x = acc[0] + bias[lane * 2 + 0];
        r.y = acc[1] + bias[lane * 2 + 1];
        if (RELU) { r.x = fmaxf(r.x, 0.f); r.y = fmaxf(r.y, 0.f); }
        *(float2*)o = r;
    }
}

// ---------------- launch ----------------

extern "C" void kernel_launch(void* const* d_in, const int* in_sizes, int n_in,
                              void* d_out, int out_size, void* d_ws, size_t ws_size,
                              hipStream_t stream) {
    const float* x   = (const float*)d_in[0];
    const int*   ei  = (const int*)d_in[1];
    const float* W1  = (const float*)d_in[2];
    const float* as1 = (const float*)d_in[3];
    const float* ad1 = (const float*)d_in[4];
    const float* b1  = (const float*)d_in[5];
    const float* W2  = (const float*)d_in[6];
    const float* as2 = (const float*)d_in[7];
    const float* ad2 = (const float*)d_in[8];
    const float* b2  = (const float*)d_in[9];

    float* out_x2 = (float*)d_out;                              // [50000,128]
    float* out_h  = (float*)d_out + (size_t)N_NODES * 128;      // [50000,256]

    float* ws = (float*)d_ws;
    size_t off = 0;
    float* h1     = ws;                 off += (size_t)N_NODES * 256;  // also holds g (layer-2 pre-agg)
    float* alo    = ws + off;           off += N_NODES;                // alpha_src per node
    float* ahi    = ws + off;           off += N_NODES;                // alpha_dst per node
    int*   deg    = (int*)(ws + off);   off += N_NODES;
    int*   offs   = (int*)(ws + off);   off += N_NODES + 4;
    int*   cursor = (int*)(ws + off);   off += N_NODES;
    int*   bsum   = (int*)(ws + off);   off += 256;
    int*   esrc   = (int*)(ws + off);   off += ETOT;
    float* coef   = ws + off;           off += ETOT;

    hipMemsetAsync(deg, 0, N_NODES * sizeof(int), stream);

    int nbE = (ETOT + 255) / 256;
    int nbN = (N_NODES + 255) / 256;            // 196
    int nbW = (N_NODES * 64 + 255) / 256;       // one wave per node -> 12500 blocks

    k_deg<<<nbE, 256, 0, stream>>>(ei, deg);
    k_scan1<<<nbN, 256, 0, stream>>>(deg, offs, bsum);
    k_scan2<<<1, 256, 0, stream>>>(bsum, nbN);
    k_scan3<<<nbN, 256, 0, stream>>>(offs, bsum);
    k_copy<<<nbN, 256, 0, stream>>>(offs, cursor);
    k_scatter<<<nbE, 256, 0, stream>>>(ei, cursor, esrc);

    // ---- layer 1: h1 = x @ W1 ; attention ; out_h = relu(agg + b1)
    k_gemm<<<dim3((N_NODES + 63) / 64, 256 / 64), 256, 0, stream>>>(x, W1, h1, N_NODES, 256, 256);
    k_alpha<<<nbW, 256, 0, stream>>>(h1, as1, ad1, alo, ahi, 256);
    k_coef<<<nbW, 256, 0, stream>>>(offs, esrc, alo, ahi, coef);
    k_aggregate<256, true><<<nbW, 256, 0, stream>>>(offs, esrc, coef, h1, b1, out_h);

    // ---- layer 2: g = out_h @ W2 ; attention ; out_x2 = agg + b2
    k_gemm<<<dim3((N_NODES + 63) / 64, 128 / 64), 256, 0, stream>>>(out_h, W2, h1, N_NODES, 128, 256);
    k_alpha<<<nbW, 256, 0, stream>>>(h1, as2, ad2, alo, ahi, 128);
    k_coef<<<nbW, 256, 0, stream>>>(offs, esrc, alo, ahi, coef);
    k_aggregate<128, false><<<nbW, 256, 0, stream>>>(offs, esrc, coef, h1, b2, out_x2);
}

// Round 4
// 413.983 us; speedup vs baseline: 1.2851x; 1.2851x over previous
//
#include <hip/hip_runtime.h>
#include <hip/hip_bf16.h>

#define N_NODES 50000
#define E0      800000
#define ETOT    850000

typedef __bf16 bf16x8 __attribute__((ext_vector_type(8)));
typedef float  f32x4  __attribute__((ext_vector_type(4)));

static __device__ __forceinline__ float b2f(ushort u) {
    union { uint u; float f; } x; x.u = ((uint)u) << 16; return x.f;
}
static __device__ __forceinline__ ushort f2bf(float f) {
    uint u = __builtin_bit_cast(uint, f);
    uint r = (u + 0x7FFFu + ((u >> 16) & 1u)) >> 16;   // RNE; inputs finite
    return (ushort)r;
}

// ---------------- CSR build ----------------

__global__ __launch_bounds__(256) void k_deg(const int* __restrict__ ei, int* __restrict__ deg) {
    int e = blockIdx.x * 256 + threadIdx.x;
    if (e >= ETOT) return;
    int dst = (e < E0) ? ei[E0 + e] : (e - E0);
    atomicAdd(&deg[dst], 1);
}

__global__ __launch_bounds__(256) void k_scan1(const int* __restrict__ deg, int* __restrict__ offs,
                                               int* __restrict__ bsum) {
    __shared__ int buf[256];
    int tid = threadIdx.x;
    int i = blockIdx.x * 256 + tid;
    int v = (i < N_NODES) ? deg[i] : 0;
    buf[tid] = v;
    __syncthreads();
    for (int off = 1; off < 256; off <<= 1) {
        int t = (tid >= off) ? buf[tid - off] : 0;
        __syncthreads();
        buf[tid] += t;
        __syncthreads();
    }
    if (i < N_NODES) offs[i + 1] = buf[tid];
    if (tid == 255) bsum[blockIdx.x] = buf[255];
}

__global__ __launch_bounds__(256) void k_scan2(int* __restrict__ bsum, int nb) {
    __shared__ int buf[256];
    int tid = threadIdx.x;
    int v = (tid < nb) ? bsum[tid] : 0;
    buf[tid] = v;
    __syncthreads();
    for (int off = 1; off < 256; off <<= 1) {
        int t = (tid >= off) ? buf[tid - off] : 0;
        __syncthreads();
        buf[tid] += t;
        __syncthreads();
    }
    if (tid < nb) bsum[tid] = buf[tid] - v;
}

__global__ __launch_bounds__(256) void k_scan3(int* __restrict__ offs, const int* __restrict__ bsum) {
    int tid = threadIdx.x;
    int i = blockIdx.x * 256 + tid;
    if (i < N_NODES) offs[i + 1] += bsum[blockIdx.x];
    if (i == 0) offs[0] = 0;
}

__global__ __launch_bounds__(256) void k_copy(const int* __restrict__ offs, int* __restrict__ cursor) {
    int i = blockIdx.x * 256 + threadIdx.x;
    if (i < N_NODES) cursor[i] = offs[i];
}

__global__ __launch_bounds__(256) void k_scatter(const int* __restrict__ ei, int* __restrict__ cursor,
                                                 int* __restrict__ esrc) {
    int e = blockIdx.x * 256 + threadIdx.x;
    if (e >= ETOT) return;
    int src, dst;
    if (e < E0) { src = ei[e]; dst = ei[E0 + e]; }
    else        { src = e - E0; dst = src; }
    int pos = atomicAdd(&cursor[dst], 1);
    esrc[pos] = src;
}

// ---------------- fp32 -> bf16 hi/lo split (elementwise, 4/thread) ----------------

__global__ __launch_bounds__(256) void k_split(const float* __restrict__ in, ushort* __restrict__ hi,
                                               ushort* __restrict__ lo, int n4) {
    int i = blockIdx.x * 256 + threadIdx.x;
    if (i >= n4) return;
    float4 v = *(const float4*)(in + (size_t)i * 4);
    ushort4 h;
    h.x = f2bf(v.x); h.y = f2bf(v.y); h.z = f2bf(v.z); h.w = f2bf(v.w);
    *(ushort4*)(hi + (size_t)i * 4) = h;
    if (lo) {
        ushort4 l;
        l.x = f2bf(v.x - b2f(h.x)); l.y = f2bf(v.y - b2f(h.y));
        l.z = f2bf(v.z - b2f(h.z)); l.w = f2bf(v.w - b2f(h.w));
        *(ushort4*)(lo + (size_t)i * 4) = l;
    }
}

// W [K][N] fp32 -> Wt_hi/Wt_lo [N][K] bf16 (tiny)
__global__ __launch_bounds__(256) void k_splitT(const float* __restrict__ W, ushort* __restrict__ th,
                                                ushort* __restrict__ tl, int K, int N) {
    int i = blockIdx.x * 256 + threadIdx.x;
    if (i >= K * N) return;
    int n = i / K, k = i - n * K;
    float v = W[(size_t)k * N + n];
    ushort h = f2bf(v);
    th[(size_t)n * K + k] = h;
    if (tl) tl[(size_t)n * K + k] = f2bf(v - b2f(h));
}

// ---------------- bf16 MFMA GEMM: Cb[M][Nn](bf16) = A[M][K] @ Bt[Nn][K]^T ----------------
// 128x128 tile, 4 waves (2x2), 64x64 per wave = 4x4 frags of 16x16, K-step 32, LDS-free.
// SPLIT: C = Ah*Bh + Ah*Bl + Al*Bh (bf16 hi/lo residual split, fp32-grade accuracy)

template <bool SPLIT>
__global__ __launch_bounds__(256) void k_gemm_mfma(const ushort* __restrict__ Ah, const ushort* __restrict__ Al,
                                                   const ushort* __restrict__ Bth, const ushort* __restrict__ Btl,
                                                   ushort* __restrict__ Cb, int M, int Nn, int K) {
    int tid = threadIdx.x;
    int wid = tid >> 6, lane = tid & 63;
    int wr = wid >> 1, wc = wid & 1;
    int bm = blockIdx.x * 128, bn = blockIdx.y * 128;
    int lr = lane & 15, lg = lane >> 4;

    f32x4 acc[4][4] = {};

    for (int kt = 0; kt < K; kt += 32) {
        bf16x8 a_h[4], a_l[4], b_h[4], b_l[4];
#pragma unroll
        for (int m = 0; m < 4; ++m) {
            int row = bm + wr * 64 + m * 16 + lr;
            if (row >= M) row = M - 1;
            size_t o = (size_t)row * K + kt + lg * 8;
            a_h[m] = *(const bf16x8*)(Ah + o);
            if (SPLIT) a_l[m] = *(const bf16x8*)(Al + o);
        }
#pragma unroll
        for (int n = 0; n < 4; ++n) {
            int col = bn + wc * 64 + n * 16 + lr;
            size_t o = (size_t)col * K + kt + lg * 8;
            b_h[n] = *(const bf16x8*)(Bth + o);
            if (SPLIT) b_l[n] = *(const bf16x8*)(Btl + o);
        }
#pragma unroll
        for (int m = 0; m < 4; ++m)
#pragma unroll
            for (int n = 0; n < 4; ++n) {
                acc[m][n] = __builtin_amdgcn_mfma_f32_16x16x32_bf16(a_h[m], b_h[n], acc[m][n], 0, 0, 0);
                if (SPLIT) {
                    acc[m][n] = __builtin_amdgcn_mfma_f32_16x16x32_bf16(a_h[m], b_l[n], acc[m][n], 0, 0, 0);
                    acc[m][n] = __builtin_amdgcn_mfma_f32_16x16x32_bf16(a_l[m], b_h[n], acc[m][n], 0, 0, 0);
                }
            }
    }
    // C/D layout: col = lane&15, row = (lane>>4)*4 + reg   [m89-verified]
#pragma unroll
    for (int m = 0; m < 4; ++m)
#pragma unroll
        for (int r = 0; r < 4; ++r) {
            int row = bm + wr * 64 + m * 16 + lg * 4 + r;
            if (row < M) {
#pragma unroll
                for (int n = 0; n < 4; ++n) {
                    int col = bn + wc * 64 + n * 16 + lr;
                    Cb[(size_t)row * Nn + col] = f2bf(acc[m][n][r]);
                }
            }
        }
}

// ---------------- per-node kernels (one wave / node), bf16 h rows ----------------

template <int F>
__global__ __launch_bounds__(256) void k_alpha(const ushort* __restrict__ H, const float* __restrict__ a_src,
                                               const float* __restrict__ a_dst, float* __restrict__ as,
                                               float* __restrict__ ad) {
    int gw = (blockIdx.x * 256 + threadIdx.x) >> 6;
    int lane = threadIdx.x & 63;
    if (gw >= N_NODES) return;
    float s = 0.f, d = 0.f;
    if (F == 256) {
        ushort4 v = *(const ushort4*)(H + (size_t)gw * 256 + lane * 4);
        float4 cs = *(const float4*)(a_src + lane * 4);
        float4 cd = *(const float4*)(a_dst + lane * 4);
        float f0 = b2f(v.x), f1 = b2f(v.y), f2 = b2f(v.z), f3 = b2f(v.w);
        s = f0 * cs.x + f1 * cs.y + f2 * cs.z + f3 * cs.w;
        d = f0 * cd.x + f1 * cd.y + f2 * cd.z + f3 * cd.w;
    } else {
        ushort2 v = *(const ushort2*)(H + (size_t)gw * 128 + lane * 2);
        float2 cs = *(const float2*)(a_src + lane * 2);
        float2 cd = *(const float2*)(a_dst + lane * 2);
        float f0 = b2f(v.x), f1 = b2f(v.y);
        s = f0 * cs.x + f1 * cs.y;
        d = f0 * cd.x + f1 * cd.y;
    }
    for (int o = 32; o; o >>= 1) { s += __shfl_down(s, o); d += __shfl_down(d, o); }
    if (lane == 0) { as[gw] = s; ad[gw] = d; }
}

__global__ __launch_bounds__(256) void k_coef(const int* __restrict__ offs, const int* __restrict__ esrc,
                                              const float* __restrict__ as, const float* __restrict__ ad,
                                              float* __restrict__ coef) {
    int gw = (blockIdx.x * 256 + threadIdx.x) >> 6;
    int lane = threadIdx.x & 63;
    if (gw >= N_NODES) return;
    int s0 = offs[gw], s1 = offs[gw + 1];
    float adi = ad[gw];
    float m = -1e30f;
    for (int k = s0 + lane; k < s1; k += 64) {
        float ev = as[esrc[k]] + adi;
        ev = ev > 0.f ? ev : 0.2f * ev;
        m = fmaxf(m, ev);
    }
    for (int o = 32; o; o >>= 1) m = fmaxf(m, __shfl_xor(m, o));
    float sum = 0.f;
    for (int k = s0 + lane; k < s1; k += 64) {
        float ev = as[esrc[k]] + adi;
        ev = ev > 0.f ? ev : 0.2f * ev;
        sum += __expf(ev - m);
    }
    for (int o = 32; o; o >>= 1) sum += __shfl_xor(sum, o);
    float inv = 1.f / sum;
    for (int k = s0 + lane; k < s1; k += 64) {
        float ev = as[esrc[k]] + adi;
        ev = ev > 0.f ? ev : 0.2f * ev;
        coef[k] = __expf(ev - m) * inv;
    }
}

// gather bf16 rows, fp32 accumulate; epilogue: +bias (, relu), write fp32 out
// and optionally bf16 hi/lo split of the result (for the next layer's GEMM A).
template <int F, bool RELU, bool WH, bool WL>
__global__ __launch_bounds__(256) void k_agg(const int* __restrict__ offs, const int* __restrict__ esrc,
                                             const float* __restrict__ coef, const ushort* __restrict__ H,
                                             const float* __restrict__ bias, float* __restrict__ out,
                                             ushort* __restrict__ oh, ushort* __restrict__ ol) {
    constexpr int V = F / 64;
    int gw = (blockIdx.x * 256 + threadIdx.x) >> 6;
    int lane = threadIdx.x & 63;
    if (gw >= N_NODES) return;
    int s0 = offs[gw], s1 = offs[gw + 1];
    float acc[V] = {};
    int k = s0;
    for (; k + 1 < s1; k += 2) {
        float c0 = coef[k], c1 = coef[k + 1];
        int r0 = esrc[k], r1 = esrc[k + 1];
        if (V == 4) {
            ushort4 v0 = *(const ushort4*)(H + (size_t)r0 * F + lane * 4);
            ushort4 v1 = *(const ushort4*)(H + (size_t)r1 * F + lane * 4);
            acc[0] += c0 * b2f(v0.x) + c1 * b2f(v1.x);
            acc[1] += c0 * b2f(v0.y) + c1 * b2f(v1.y);
            acc[2] += c0 * b2f(v0.z) + c1 * b2f(v1.z);
            acc[3] += c0 * b2f(v0.w) + c1 * b2f(v1.w);
        } else {
            ushort2 v0 = *(const ushort2*)(H + (size_t)r0 * F + lane * 2);
            ushort2 v1 = *(const ushort2*)(H + (size_t)r1 * F + lane * 2);
            acc[0] += c0 * b2f(v0.x) + c1 * b2f(v1.x);
            acc[1] += c0 * b2f(v0.y) + c1 * b2f(v1.y);
        }
    }
    if (k < s1) {
        float c0 = coef[k];
        int r0 = esrc[k];
        if (V == 4) {
            ushort4 v0 = *(const ushort4*)(H + (size_t)r0 * F + lane * 4);
            acc[0] += c0 * b2f(v0.x); acc[1] += c0 * b2f(v0.y);
            acc[2] += c0 * b2f(v0.z); acc[3] += c0 * b2f(v0.w);
        } else {
            ushort2 v0 = *(const ushort2*)(H + (size_t)r0 * F + lane * 2);
            acc[0] += c0 * b2f(v0.x); acc[1] += c0 * b2f(v0.y);
        }
    }
    float r[V];
#pragma unroll
    for (int j = 0; j < V; ++j) {
        r[j] = acc[j] + bias[lane * V + j];
        if (RELU) r[j] = fmaxf(r[j], 0.f);
    }
    if (V == 4) {
        float4 o = make_float4(r[0], r[1], r[2], r[3]);
        *(float4*)(out + (size_t)gw * F + lane * 4) = o;
    } else {
        float2 o = make_float2(r[0], r[1]);
        *(float2*)(out + (size_t)gw * F + lane * 2) = o;
    }
    if (WH) {
        ushort h[V];
#pragma unroll
        for (int j = 0; j < V; ++j) h[j] = f2bf(r[j]);
        if (V == 4) {
            ushort4 hv; hv.x = h[0]; hv.y = h[1]; hv.z = h[2]; hv.w = h[3];
            *(ushort4*)(oh + (size_t)gw * F + lane * 4) = hv;
            if (WL) {
                ushort4 lv;
                lv.x = f2bf(r[0] - b2f(h[0])); lv.y = f2bf(r[1] - b2f(h[1]));
                lv.z = f2bf(r[2] - b2f(h[2])); lv.w = f2bf(r[3] - b2f(h[3]));
                *(ushort4*)(ol + (size_t)gw * F + lane * 4) = lv;
            }
        }
    }
}

// ---------------- launch ----------------

static inline size_t al256(size_t x) { return (x + 255) & ~(size_t)255; }

extern "C" void kernel_launch(void* const* d_in, const int* in_sizes, int n_in,
                              void* d_out, int out_size, void* d_ws, size_t ws_size,
                              hipStream_t stream) {
    const float* x   = (const float*)d_in[0];
    const int*   ei  = (const int*)d_in[1];
    const float* W1  = (const float*)d_in[2];
    const float* as1 = (const float*)d_in[3];
    const float* ad1 = (const float*)d_in[4];
    const float* b1  = (const float*)d_in[5];
    const float* W2  = (const float*)d_in[6];
    const float* as2 = (const float*)d_in[7];
    const float* ad2 = (const float*)d_in[8];
    const float* b2  = (const float*)d_in[9];

    float* out_x2 = (float*)d_out;                          // [50000,128]
    float* out_h  = (float*)d_out + (size_t)N_NODES * 128;  // [50000,256]

    const size_t NM256 = (size_t)N_NODES * 256 * 2;  // bf16 [50000][256] bytes
    char* base = (char*)d_ws;
    size_t off = 0;
    auto take = [&](size_t bytes) { char* p = base + off; off = al256(off + bytes); return p; };

    ushort* xh   = (ushort*)take(NM256);
    ushort* h1b  = (ushort*)take(NM256);            // layer1 GEMM out; reused for layer2 (gb)
    ushort* hph  = (ushort*)take(NM256);            // bf16(hi) of relu output
    ushort* w1th = (ushort*)take(256 * 256 * 2);
    ushort* w2th = (ushort*)take(256 * 128 * 2);
    float*  alo  = (float*)take(N_NODES * 4);
    float*  ahi  = (float*)take(N_NODES * 4);
    int*    deg  = (int*)take(N_NODES * 4);
    int*    offs = (int*)take((N_NODES + 4) * 4);
    int*    curs = (int*)take(N_NODES * 4);
    int*    bsum = (int*)take(1024);
    int*    esrc = (int*)take((size_t)ETOT * 4);
    float*  coef = (float*)take((size_t)ETOT * 4);
    // lo arrays (residual split) only if workspace allows
    ushort* xl   = (ushort*)take(NM256);
    ushort* hpl  = (ushort*)take(NM256);
    ushort* w1tl = (ushort*)take(256 * 256 * 2);
    ushort* w2tl = (ushort*)take(256 * 128 * 2);
    bool split = (off <= ws_size);
    if (!split) { xl = nullptr; hpl = nullptr; w1tl = nullptr; w2tl = nullptr; }

    hipMemsetAsync(deg, 0, N_NODES * sizeof(int), stream);

    int nbE = (ETOT + 255) / 256;
    int nbN = (N_NODES + 255) / 256;
    int nbW = (N_NODES * 64 + 255) / 256;

    // CSR by dst
    k_deg<<<nbE, 256, 0, stream>>>(ei, deg);
    k_scan1<<<nbN, 256, 0, stream>>>(deg, offs, bsum);
    k_scan2<<<1, 256, 0, stream>>>(bsum, nbN);
    k_scan3<<<nbN, 256, 0, stream>>>(offs, bsum);
    k_copy<<<nbN, 256, 0, stream>>>(offs, curs);
    k_scatter<<<nbE, 256, 0, stream>>>(ei, curs, esrc);

    // operand conversion
    int n4x = N_NODES * 256 / 4;
    k_split<<<(n4x + 255) / 256, 256, 0, stream>>>(x, xh, xl, n4x);
    k_splitT<<<(256 * 256 + 255) / 256, 256, 0, stream>>>(W1, w1th, w1tl, 256, 256);
    k_splitT<<<(256 * 128 + 255) / 256, 256, 0, stream>>>(W2, w2th, w2tl, 256, 128);

    dim3 g1((N_NODES + 127) / 128, 2), g2((N_NODES + 127) / 128, 1);

    // ---- layer 1
    if (split) k_gemm_mfma<true ><<<g1, 256, 0, stream>>>(xh, xl, w1th, w1tl, h1b, N_NODES, 256, 256);
    else       k_gemm_mfma<false><<<g1, 256, 0, stream>>>(xh, xl, w1th, w1tl, h1b, N_NODES, 256, 256);
    k_alpha<256><<<nbW, 256, 0, stream>>>(h1b, as1, ad1, alo, ahi);
    k_coef<<<nbW, 256, 0, stream>>>(offs, esrc, alo, ahi, coef);
    if (split) k_agg<256, true, true, true ><<<nbW, 256, 0, stream>>>(offs, esrc, coef, h1b, b1, out_h, hph, hpl);
    else       k_agg<256, true, true, false><<<nbW, 256, 0, stream>>>(offs, esrc, coef, h1b, b1, out_h, hph, hpl);

    // ---- layer 2 (gb reuses h1b buffer)
    ushort* gb = h1b;
    if (split) k_gemm_mfma<true ><<<g2, 256, 0, stream>>>(hph, hpl, w2th, w2tl, gb, N_NODES, 128, 256);
    else       k_gemm_mfma<false><<<g2, 256, 0, stream>>>(hph, hpl, w2th, w2tl, gb, N_NODES, 128, 256);
    k_alpha<128><<<nbW, 256, 0, stream>>>(gb, as2, ad2, alo, ahi);
    k_coef<<<nbW, 256, 0, stream>>>(offs, esrc, alo, ahi, coef);
    k_agg<128, false, false, false><<<nbW, 256, 0, stream>>>(offs, esrc, coef, gb, b2, out_x2, nullptr, nullptr);
}

// Round 8
// 355.894 us; speedup vs baseline: 1.4948x; 1.1632x over previous
//
#include <hip/hip_runtime.h>
#include <hip/hip_bf16.h>

#define N_NODES 50000
#define E0      800000
#define ETOT    850000

typedef __bf16 bf16x8 __attribute__((ext_vector_type(8)));
typedef float  f32x4  __attribute__((ext_vector_type(4)));
typedef ushort u16x8  __attribute__((ext_vector_type(8)));
union B8 { u16x8 u; bf16x8 b; };

static __device__ __forceinline__ float b2f(ushort u) {
    union { uint u; float f; } x; x.u = ((uint)u) << 16; return x.f;
}
static __device__ __forceinline__ ushort f2bf(float f) {
    uint u = __builtin_bit_cast(uint, f);
    uint r = (u + 0x7FFFu + ((u >> 16) & 1u)) >> 16;   // RNE; inputs finite
    return (ushort)r;
}

// ---------------- CSR build ----------------

__global__ __launch_bounds__(256) void k_deg(const int* __restrict__ ei, int* __restrict__ deg) {
    int e = blockIdx.x * 256 + threadIdx.x;
    if (e >= ETOT) return;
    int dst = (e < E0) ? ei[E0 + e] : (e - E0);
    atomicAdd(&deg[dst], 1);
}

__global__ __launch_bounds__(256) void k_scan1(const int* __restrict__ deg, int* __restrict__ offs,
                                               int* __restrict__ bsum) {
    __shared__ int buf[256];
    int tid = threadIdx.x;
    int i = blockIdx.x * 256 + tid;
    int v = (i < N_NODES) ? deg[i] : 0;
    buf[tid] = v;
    __syncthreads();
    for (int off = 1; off < 256; off <<= 1) {
        int t = (tid >= off) ? buf[tid - off] : 0;
        __syncthreads();
        buf[tid] += t;
        __syncthreads();
    }
    if (i < N_NODES) offs[i + 1] = buf[tid];
    if (tid == 255) bsum[blockIdx.x] = buf[255];
}

__global__ __launch_bounds__(256) void k_scan2(int* __restrict__ bsum, int nb) {
    __shared__ int buf[256];
    int tid = threadIdx.x;
    int v = (tid < nb) ? bsum[tid] : 0;
    buf[tid] = v;
    __syncthreads();
    for (int off = 1; off < 256; off <<= 1) {
        int t = (tid >= off) ? buf[tid - off] : 0;
        __syncthreads();
        buf[tid] += t;
        __syncthreads();
    }
    if (tid < nb) bsum[tid] = buf[tid] - v;
}

__global__ __launch_bounds__(256) void k_scan3(int* __restrict__ offs, const int* __restrict__ bsum) {
    int tid = threadIdx.x;
    int i = blockIdx.x * 256 + tid;
    if (i < N_NODES) offs[i + 1] += bsum[blockIdx.x];
    if (i == 0) offs[0] = 0;
}

__global__ __launch_bounds__(256) void k_copy(const int* __restrict__ offs, int* __restrict__ cursor) {
    int i = blockIdx.x * 256 + threadIdx.x;
    if (i < N_NODES) cursor[i] = offs[i];
}

__global__ __launch_bounds__(256) void k_scatter(const int* __restrict__ ei, int* __restrict__ cursor,
                                                 int* __restrict__ esrc) {
    int e = blockIdx.x * 256 + threadIdx.x;
    if (e >= ETOT) return;
    int src, dst;
    if (e < E0) { src = ei[e]; dst = ei[E0 + e]; }
    else        { src = e - E0; dst = src; }
    int pos = atomicAdd(&cursor[dst], 1);
    esrc[pos] = src;
}

// W [K][N] fp32 -> Wt_hi/Wt_lo [N][K] bf16 (tiny)
__global__ __launch_bounds__(256) void k_splitT(const float* __restrict__ W, ushort* __restrict__ th,
                                                ushort* __restrict__ tl, int K, int N) {
    int i = blockIdx.x * 256 + threadIdx.x;
    if (i >= K * N) return;
    int n = i / K, k = i - n * K;
    float v = W[(size_t)k * N + n];
    ushort h = f2bf(v);
    th[(size_t)n * K + k] = h;
    tl[(size_t)n * K + k] = f2bf(v - b2f(h));
}

// ---------------- MFMA GEMM, fp32 A with in-register hi/lo split ----------------
// Cb[M][Nn](bf16) = A[M][K](fp32) @ Bt[Nn][K]^T (pre-split bf16 hi/lo)
// 128x128 tile, 4 waves (2x2), 64x64/wave = 4x4 frags of 16x16x32, LDS-free.
// acc = Ah*Bh + Al*Bh + Ah*Bl  (Al*Bl ~2^-16, dropped)

static __device__ __forceinline__ void split8(const float* __restrict__ p, bf16x8& hi, bf16x8& lo) {
    float4 v0 = *(const float4*)p;
    float4 v1 = *(const float4*)(p + 4);
    float vv[8] = { v0.x, v0.y, v0.z, v0.w, v1.x, v1.y, v1.z, v1.w };
    B8 H, L;
#pragma unroll
    for (int i = 0; i < 8; ++i) {
        uint u = __builtin_bit_cast(uint, vv[i]);
        H.u[i] = (ushort)(u >> 16);                               // trunc-bf16 hi
        float hf = __builtin_bit_cast(float, u & 0xffff0000u);
        L.u[i] = (ushort)(__builtin_bit_cast(uint, vv[i] - hf) >> 16);  // residual (exact sub)
    }
    hi = H.b; lo = L.b;
}

__global__ __launch_bounds__(256) void k_gemm_mfma(const float* __restrict__ A,
                                                   const ushort* __restrict__ Bth, const ushort* __restrict__ Btl,
                                                   ushort* __restrict__ Cb, int M, int Nn, int K) {
    int tid = threadIdx.x;
    int wid = tid >> 6, lane = tid & 63;
    int wr = wid >> 1, wc = wid & 1;
    int bm = blockIdx.x * 128, bn = blockIdx.y * 128;
    int lr = lane & 15, lg = lane >> 4;

    f32x4 acc[4][4] = {};

    for (int kt = 0; kt < K; kt += 32) {
        bf16x8 a_h[4], a_l[4], b_h[4], b_l[4];
#pragma unroll
        for (int m = 0; m < 4; ++m) {
            int row = bm + wr * 64 + m * 16 + lr;
            if (row >= M) row = M - 1;
            split8(A + (size_t)row * K + kt + lg * 8, a_h[m], a_l[m]);
        }
#pragma unroll
        for (int n = 0; n < 4; ++n) {
            int col = bn + wc * 64 + n * 16 + lr;
            size_t o = (size_t)col * K + kt + lg * 8;
            b_h[n] = *(const bf16x8*)(Bth + o);
            b_l[n] = *(const bf16x8*)(Btl + o);
        }
#pragma unroll
        for (int m = 0; m < 4; ++m)
#pragma unroll
            for (int n = 0; n < 4; ++n) {
                acc[m][n] = __builtin_amdgcn_mfma_f32_16x16x32_bf16(a_h[m], b_h[n], acc[m][n], 0, 0, 0);
                acc[m][n] = __builtin_amdgcn_mfma_f32_16x16x32_bf16(a_l[m], b_h[n], acc[m][n], 0, 0, 0);
                acc[m][n] = __builtin_amdgcn_mfma_f32_16x16x32_bf16(a_h[m], b_l[n], acc[m][n], 0, 0, 0);
            }
    }
    // C/D layout: col = lane&15, row = (lane>>4)*4 + reg   [m89-verified]
#pragma unroll
    for (int m = 0; m < 4; ++m)
#pragma unroll
        for (int r = 0; r < 4; ++r) {
            int row = bm + wr * 64 + m * 16 + lg * 4 + r;
            if (row < M) {
#pragma unroll
                for (int n = 0; n < 4; ++n) {
                    int col = bn + wc * 64 + n * 16 + lr;
                    Cb[(size_t)row * Nn + col] = f2bf(acc[m][n][r]);
                }
            }
        }
}

// ---------------- per-node kernels (one wave / node), bf16 h rows ----------------

template <int F>
__global__ __launch_bounds__(256) void k_alpha(const ushort* __restrict__ H, const float* __restrict__ a_src,
                                               const float* __restrict__ a_dst, float* __restrict__ as,
                                               float* __restrict__ ad) {
    int gw = (blockIdx.x * 256 + threadIdx.x) >> 6;
    int lane = threadIdx.x & 63;
    if (gw >= N_NODES) return;
    float s = 0.f, d = 0.f;
    if (F == 256) {
        ushort4 v = *(const ushort4*)(H + (size_t)gw * 256 + lane * 4);
        float4 cs = *(const float4*)(a_src + lane * 4);
        float4 cd = *(const float4*)(a_dst + lane * 4);
        float f0 = b2f(v.x), f1 = b2f(v.y), f2 = b2f(v.z), f3 = b2f(v.w);
        s = f0 * cs.x + f1 * cs.y + f2 * cs.z + f3 * cs.w;
        d = f0 * cd.x + f1 * cd.y + f2 * cd.z + f3 * cd.w;
    } else {
        ushort2 v = *(const ushort2*)(H + (size_t)gw * 128 + lane * 2);
        float2 cs = *(const float2*)(a_src + lane * 2);
        float2 cd = *(const float2*)(a_dst + lane * 2);
        float f0 = b2f(v.x), f1 = b2f(v.y);
        s = f0 * cs.x + f1 * cs.y;
        d = f0 * cd.x + f1 * cd.y;
    }
    for (int o = 32; o; o >>= 1) { s += __shfl_down(s, o); d += __shfl_down(d, o); }
    if (lane == 0) { as[gw] = s; ad[gw] = d; }
}

// ---- fused online-softmax aggregation: one wave per node, single edge pass ----
// e_k = leakyrelu(as[src_k] + ad[i]); online max m, sum ssum, rescaled acc.
template <int F, bool RELU>
__global__ __launch_bounds__(256) void k_aggf(const int* __restrict__ offs, const int* __restrict__ esrc,
                                              const float* __restrict__ as, const float* __restrict__ ad,
                                              const ushort* __restrict__ H, const float* __restrict__ bias,
                                              float* __restrict__ out) {
    constexpr int V = F / 64;
    int gw = (blockIdx.x * 256 + threadIdx.x) >> 6;
    int lane = threadIdx.x & 63;
    if (gw >= N_NODES) return;
    int s0 = offs[gw], s1 = offs[gw + 1];
    float adi = ad[gw];
    float m = -1e30f, ssum = 0.f;
    float acc[V] = {};
    int k = s0;
    for (; k + 1 < s1; k += 2) {
        int r0 = esrc[k], r1 = esrc[k + 1];
        float row0[V], row1[V];
        if (V == 4) {
            ushort4 v0 = *(const ushort4*)(H + (size_t)r0 * F + lane * 4);
            ushort4 v1 = *(const ushort4*)(H + (size_t)r1 * F + lane * 4);
            row0[0] = b2f(v0.x); row0[1] = b2f(v0.y); row0[2] = b2f(v0.z); row0[3] = b2f(v0.w);
            row1[0] = b2f(v1.x); row1[1] = b2f(v1.y); row1[2] = b2f(v1.z); row1[3] = b2f(v1.w);
        } else {
            ushort2 v0 = *(const ushort2*)(H + (size_t)r0 * F + lane * 2);
            ushort2 v1 = *(const ushort2*)(H + (size_t)r1 * F + lane * 2);
            row0[0] = b2f(v0.x); row0[1] = b2f(v0.y);
            row1[0] = b2f(v1.x); row1[1] = b2f(v1.y);
        }
        float e0 = as[r0] + adi; e0 = e0 > 0.f ? e0 : 0.2f * e0;
        float e1 = as[r1] + adi; e1 = e1 > 0.f ? e1 : 0.2f * e1;
        float e01 = fmaxf(e0, e1);
        if (e01 <= m) {                       // wave-uniform branch
            float w0 = __expf(e0 - m), w1 = __expf(e1 - m);
            ssum += w0 + w1;
#pragma unroll
            for (int j = 0; j < V; ++j) acc[j] += w0 * row0[j] + w1 * row1[j];
        } else {
            float sc = __expf(m - e01);
            float w0 = __expf(e0 - e01), w1 = __expf(e1 - e01);
            ssum = ssum * sc + w0 + w1;
#pragma unroll
            for (int j = 0; j < V; ++j) acc[j] = acc[j] * sc + w0 * row0[j] + w1 * row1[j];
            m = e01;
        }
    }
    if (k < s1) {
        int r0 = esrc[k];
        float row0[V];
        if (V == 4) {
            ushort4 v0 = *(const ushort4*)(H + (size_t)r0 * F + lane * 4);
            row0[0] = b2f(v0.x); row0[1] = b2f(v0.y); row0[2] = b2f(v0.z); row0[3] = b2f(v0.w);
        } else {
            ushort2 v0 = *(const ushort2*)(H + (size_t)r0 * F + lane * 2);
            row0[0] = b2f(v0.x); row0[1] = b2f(v0.y);
        }
        float e0 = as[r0] + adi; e0 = e0 > 0.f ? e0 : 0.2f * e0;
        if (e0 <= m) {
            float w0 = __expf(e0 - m);
            ssum += w0;
#pragma unroll
            for (int j = 0; j < V; ++j) acc[j] += w0 * row0[j];
        } else {
            float sc = __expf(m - e0);
            ssum = ssum * sc + 1.0f;
#pragma unroll
            for (int j = 0; j < V; ++j) acc[j] = acc[j] * sc + row0[j];
            m = e0;
        }
    }
    float inv = 1.f / ssum;
    float r[V];
#pragma unroll
    for (int j = 0; j < V; ++j) {
        r[j] = acc[j] * inv + bias[lane * V + j];
        if (RELU) r[j] = fmaxf(r[j], 0.f);
    }
    if (V == 4) *(float4*)(out + (size_t)gw * F + lane * 4) = make_float4(r[0], r[1], r[2], r[3]);
    else        *(float2*)(out + (size_t)gw * F + lane * 2) = make_float2(r[0], r[1]);
}

// ---------------- launch ----------------

static inline size_t al256(size_t x) { return (x + 255) & ~(size_t)255; }

extern "C" void kernel_launch(void* const* d_in, const int* in_sizes, int n_in,
                              void* d_out, int out_size, void* d_ws, size_t ws_size,
                              hipStream_t stream) {
    const float* x   = (const float*)d_in[0];
    const int*   ei  = (const int*)d_in[1];
    const float* W1  = (const float*)d_in[2];
    const float* as1 = (const float*)d_in[3];
    const float* ad1 = (const float*)d_in[4];
    const float* b1  = (const float*)d_in[5];
    const float* W2  = (const float*)d_in[6];
    const float* as2 = (const float*)d_in[7];
    const float* ad2 = (const float*)d_in[8];
    const float* b2  = (const float*)d_in[9];

    float* out_x2 = (float*)d_out;                          // [50000,128]
    float* out_h  = (float*)d_out + (size_t)N_NODES * 128;  // [50000,256] fp32

    const size_t NM256 = (size_t)N_NODES * 256 * 2;         // bf16 [50000][256]
    char* base = (char*)d_ws;
    size_t off = 0;
    auto take = [&](size_t bytes) { char* p = base + off; off = al256(off + bytes); return p; };

    ushort* h1b  = (ushort*)take(NM256);            // layer1 GEMM out (bf16); reused as layer2 gb
    ushort* w1th = (ushort*)take(256 * 256 * 2);
    ushort* w1tl = (ushort*)take(256 * 256 * 2);
    ushort* w2th = (ushort*)take(256 * 128 * 2);
    ushort* w2tl = (ushort*)take(256 * 128 * 2);
    float*  asb  = (float*)take(N_NODES * 4);
    float*  adb  = (float*)take(N_NODES * 4);
    int*    deg  = (int*)take(N_NODES * 4);
    int*    offs = (int*)take((N_NODES + 4) * 4);
    int*    curs = (int*)take(N_NODES * 4);
    int*    bsum = (int*)take(1024);
    int*    esrc = (int*)take((size_t)ETOT * 4);
    (void)ws_size;

    hipMemsetAsync(deg, 0, N_NODES * sizeof(int), stream);

    int nbE = (ETOT + 255) / 256;
    int nbN = (N_NODES + 255) / 256;
    int nbW = (N_NODES * 64 + 255) / 256;       // one wave per node

    // CSR by dst
    k_deg<<<nbE, 256, 0, stream>>>(ei, deg);
    k_scan1<<<nbN, 256, 0, stream>>>(deg, offs, bsum);
    k_scan2<<<1, 256, 0, stream>>>(bsum, nbN);
    k_scan3<<<nbN, 256, 0, stream>>>(offs, bsum);
    k_copy<<<nbN, 256, 0, stream>>>(offs, curs);
    k_scatter<<<nbE, 256, 0, stream>>>(ei, curs, esrc);

    // weight transpose+split (tiny)
    k_splitT<<<(256 * 256 + 255) / 256, 256, 0, stream>>>(W1, w1th, w1tl, 256, 256);
    k_splitT<<<(256 * 128 + 255) / 256, 256, 0, stream>>>(W2, w2th, w2tl, 256, 128);

    dim3 g1((N_NODES + 127) / 128, 2), g2((N_NODES + 127) / 128, 1);

    // ---- layer 1
    k_gemm_mfma<<<g1, 256, 0, stream>>>(x, w1th, w1tl, h1b, N_NODES, 256, 256);
    k_alpha<256><<<nbW, 256, 0, stream>>>(h1b, as1, ad1, asb, adb);
    k_aggf<256, true><<<nbW, 256, 0, stream>>>(offs, esrc, asb, adb, h1b, b1, out_h);

    // ---- layer 2 (A = out_h fp32 read directly; gb reuses h1b)
    ushort* gb = h1b;
    k_gemm_mfma<<<g2, 256, 0, stream>>>(out_h, w2th, w2tl, gb, N_NODES, 128, 256);
    k_alpha<128><<<nbW, 256, 0, stream>>>(gb, as2, ad2, asb, adb);
    k_aggf<128, false><<<nbW, 256, 0, stream>>>(offs, esrc, asb, adb, gb, b2, out_x2);
}

// Round 9
// 328.394 us; speedup vs baseline: 1.6200x; 1.0837x over previous
//
#include <hip/hip_runtime.h>
#include <hip/hip_bf16.h>

#define N_NODES 50000
#define E0      800000
#define ETOT    850000

typedef __bf16 bf16x8 __attribute__((ext_vector_type(8)));
typedef float  f32x4  __attribute__((ext_vector_type(4)));
typedef ushort u16x8  __attribute__((ext_vector_type(8)));
union B8 { u16x8 u; bf16x8 b; };

static __device__ __forceinline__ float b2f(ushort u) {
    union { uint u; float f; } x; x.u = ((uint)u) << 16; return x.f;
}
static __device__ __forceinline__ ushort f2bf(float f) {
    uint u = __builtin_bit_cast(uint, f);
    uint r = (u + 0x7FFFu + ((u >> 16) & 1u)) >> 16;   // RNE; inputs finite
    return (ushort)r;
}

// ---------------- CSR build ----------------

__global__ __launch_bounds__(256) void k_deg(const int* __restrict__ ei, int* __restrict__ deg) {
    int e = blockIdx.x * 256 + threadIdx.x;
    if (e >= ETOT) return;
    int dst = (e < E0) ? ei[E0 + e] : (e - E0);
    atomicAdd(&deg[dst], 1);
}

__global__ __launch_bounds__(256) void k_scan1(const int* __restrict__ deg, int* __restrict__ offs,
                                               int* __restrict__ bsum) {
    __shared__ int buf[256];
    int tid = threadIdx.x;
    int i = blockIdx.x * 256 + tid;
    int v = (i < N_NODES) ? deg[i] : 0;
    buf[tid] = v;
    __syncthreads();
    for (int off = 1; off < 256; off <<= 1) {
        int t = (tid >= off) ? buf[tid - off] : 0;
        __syncthreads();
        buf[tid] += t;
        __syncthreads();
    }
    if (i < N_NODES) offs[i + 1] = buf[tid];
    if (tid == 255) bsum[blockIdx.x] = buf[255];
}

__global__ __launch_bounds__(256) void k_scan2(int* __restrict__ bsum, int nb) {
    __shared__ int buf[256];
    int tid = threadIdx.x;
    int v = (tid < nb) ? bsum[tid] : 0;
    buf[tid] = v;
    __syncthreads();
    for (int off = 1; off < 256; off <<= 1) {
        int t = (tid >= off) ? buf[tid - off] : 0;
        __syncthreads();
        buf[tid] += t;
        __syncthreads();
    }
    if (tid < nb) bsum[tid] = buf[tid] - v;
}

__global__ __launch_bounds__(256) void k_scan3(int* __restrict__ offs, const int* __restrict__ bsum) {
    int tid = threadIdx.x;
    int i = blockIdx.x * 256 + tid;
    if (i < N_NODES) offs[i + 1] += bsum[blockIdx.x];
    if (i == 0) offs[0] = 0;
}

__global__ __launch_bounds__(256) void k_copy(const int* __restrict__ offs, int* __restrict__ cursor) {
    int i = blockIdx.x * 256 + threadIdx.x;
    if (i < N_NODES) cursor[i] = offs[i];
}

__global__ __launch_bounds__(256) void k_scatter(const int* __restrict__ ei, int* __restrict__ cursor,
                                                 int* __restrict__ esrc) {
    int e = blockIdx.x * 256 + threadIdx.x;
    if (e >= ETOT) return;
    int src, dst;
    if (e < E0) { src = ei[e]; dst = ei[E0 + e]; }
    else        { src = e - E0; dst = src; }
    int pos = atomicAdd(&cursor[dst], 1);
    esrc[pos] = src;
}

// W [K][N] fp32 -> Wt_hi/Wt_lo [N][K] bf16 (tiny)
__global__ __launch_bounds__(256) void k_splitT(const float* __restrict__ W, ushort* __restrict__ th,
                                                ushort* __restrict__ tl, int K, int N) {
    int i = blockIdx.x * 256 + threadIdx.x;
    if (i >= K * N) return;
    int n = i / K, k = i - n * K;
    float v = W[(size_t)k * N + n];
    ushort h = f2bf(v);
    th[(size_t)n * K + k] = h;
    tl[(size_t)n * K + k] = f2bf(v - b2f(h));
}

// ---------------- MFMA GEMM, fp32 A with in-register hi/lo split ----------------
// Cb[M][Nn](bf16) = A[M][K](fp32) @ Bt[Nn][K]^T (pre-split bf16 hi/lo)
// 128x128 tile, 4 waves (2x2), 64x64/wave = 4x4 frags of 16x16x32, LDS-free.
// acc = Ah*Bh + Al*Bh + Ah*Bl  (Al*Bl ~2^-16, dropped)

static __device__ __forceinline__ void split8(const float* __restrict__ p, bf16x8& hi, bf16x8& lo) {
    float4 v0 = *(const float4*)p;
    float4 v1 = *(const float4*)(p + 4);
    float vv[8] = { v0.x, v0.y, v0.z, v0.w, v1.x, v1.y, v1.z, v1.w };
    B8 H, L;
#pragma unroll
    for (int i = 0; i < 8; ++i) {
        uint u = __builtin_bit_cast(uint, vv[i]);
        H.u[i] = (ushort)(u >> 16);                               // trunc-bf16 hi
        float hf = __builtin_bit_cast(float, u & 0xffff0000u);
        L.u[i] = (ushort)(__builtin_bit_cast(uint, vv[i] - hf) >> 16);  // residual (exact sub)
    }
    hi = H.b; lo = L.b;
}

__global__ __launch_bounds__(256) void k_gemm_mfma(const float* __restrict__ A,
                                                   const ushort* __restrict__ Bth, const ushort* __restrict__ Btl,
                                                   ushort* __restrict__ Cb, int M, int Nn, int K) {
    int tid = threadIdx.x;
    int wid = tid >> 6, lane = tid & 63;
    int wr = wid >> 1, wc = wid & 1;
    int bm = blockIdx.x * 128, bn = blockIdx.y * 128;
    int lr = lane & 15, lg = lane >> 4;

    f32x4 acc[4][4] = {};

    for (int kt = 0; kt < K; kt += 32) {
        bf16x8 a_h[4], a_l[4], b_h[4], b_l[4];
#pragma unroll
        for (int m = 0; m < 4; ++m) {
            int row = bm + wr * 64 + m * 16 + lr;
            if (row >= M) row = M - 1;
            split8(A + (size_t)row * K + kt + lg * 8, a_h[m], a_l[m]);
        }
#pragma unroll
        for (int n = 0; n < 4; ++n) {
            int col = bn + wc * 64 + n * 16 + lr;
            size_t o = (size_t)col * K + kt + lg * 8;
            b_h[n] = *(const bf16x8*)(Bth + o);
            b_l[n] = *(const bf16x8*)(Btl + o);
        }
#pragma unroll
        for (int m = 0; m < 4; ++m)
#pragma unroll
            for (int n = 0; n < 4; ++n) {
                acc[m][n] = __builtin_amdgcn_mfma_f32_16x16x32_bf16(a_h[m], b_h[n], acc[m][n], 0, 0, 0);
                acc[m][n] = __builtin_amdgcn_mfma_f32_16x16x32_bf16(a_l[m], b_h[n], acc[m][n], 0, 0, 0);
                acc[m][n] = __builtin_amdgcn_mfma_f32_16x16x32_bf16(a_h[m], b_l[n], acc[m][n], 0, 0, 0);
            }
    }
    // C/D layout: col = lane&15, row = (lane>>4)*4 + reg   [m89-verified]
#pragma unroll
    for (int m = 0; m < 4; ++m)
#pragma unroll
        for (int r = 0; r < 4; ++r) {
            int row = bm + wr * 64 + m * 16 + lg * 4 + r;
            if (row < M) {
#pragma unroll
                for (int n = 0; n < 4; ++n) {
                    int col = bn + wc * 64 + n * 16 + lr;
                    Cb[(size_t)row * Nn + col] = f2bf(acc[m][n][r]);
                }
            }
        }
}

// ---------------- per-node kernels (one wave / node), bf16 h rows ----------------

template <int F>
__global__ __launch_bounds__(256) void k_alpha(const ushort* __restrict__ H, const float* __restrict__ a_src,
                                               const float* __restrict__ a_dst, float* __restrict__ as,
                                               float* __restrict__ ad) {
    int gw = (blockIdx.x * 256 + threadIdx.x) >> 6;
    int lane = threadIdx.x & 63;
    if (gw >= N_NODES) return;
    float s = 0.f, d = 0.f;
    if (F == 256) {
        ushort4 v = *(const ushort4*)(H + (size_t)gw * 256 + lane * 4);
        float4 cs = *(const float4*)(a_src + lane * 4);
        float4 cd = *(const float4*)(a_dst + lane * 4);
        float f0 = b2f(v.x), f1 = b2f(v.y), f2 = b2f(v.z), f3 = b2f(v.w);
        s = f0 * cs.x + f1 * cs.y + f2 * cs.z + f3 * cs.w;
        d = f0 * cd.x + f1 * cd.y + f2 * cd.z + f3 * cd.w;
    } else {
        ushort2 v = *(const ushort2*)(H + (size_t)gw * 128 + lane * 2);
        float2 cs = *(const float2*)(a_src + lane * 2);
        float2 cd = *(const float2*)(a_dst + lane * 2);
        float f0 = b2f(v.x), f1 = b2f(v.y);
        s = f0 * cs.x + f1 * cs.y;
        d = f0 * cd.x + f1 * cd.y;
    }
    for (int o = 32; o; o >>= 1) { s += __shfl_down(s, o); d += __shfl_down(d, o); }
    if (lane == 0) { as[gw] = s; ad[gw] = d; }
}

// ---- fused online-softmax aggregation, 4-edge unrolled + deferred rescale ----
// e_k = leakyrelu(as[src_k] + ad[i]); running lagged max m (rescale only when
// batch max exceeds m+8 -> weights bounded by e^8, fp32-safe for deg<=~1000).
template <int F, bool RELU>
__global__ __launch_bounds__(256) void k_aggf(const int* __restrict__ offs, const int* __restrict__ esrc,
                                              const float* __restrict__ as, const float* __restrict__ ad,
                                              const ushort* __restrict__ H, const float* __restrict__ bias,
                                              float* __restrict__ out) {
    constexpr int V = F / 64;
    constexpr float THR = 8.f;
    int gw = (blockIdx.x * 256 + threadIdx.x) >> 6;
    int lane = threadIdx.x & 63;
    if (gw >= N_NODES) return;
    int s0 = offs[gw], s1 = offs[gw + 1];
    float adi = ad[gw];
    float m = -1e30f, ssum = 0.f;
    float acc[V] = {};
    int k = s0;
    for (; k + 3 < s1; k += 4) {
        int r0 = esrc[k], r1 = esrc[k + 1], r2 = esrc[k + 2], r3 = esrc[k + 3];
        float row0[V], row1[V], row2[V], row3[V];
        if (V == 4) {
            ushort4 v0 = *(const ushort4*)(H + (size_t)r0 * F + lane * 4);
            ushort4 v1 = *(const ushort4*)(H + (size_t)r1 * F + lane * 4);
            ushort4 v2 = *(const ushort4*)(H + (size_t)r2 * F + lane * 4);
            ushort4 v3 = *(const ushort4*)(H + (size_t)r3 * F + lane * 4);
            row0[0] = b2f(v0.x); row0[1] = b2f(v0.y); row0[2] = b2f(v0.z); row0[3] = b2f(v0.w);
            row1[0] = b2f(v1.x); row1[1] = b2f(v1.y); row1[2] = b2f(v1.z); row1[3] = b2f(v1.w);
            row2[0] = b2f(v2.x); row2[1] = b2f(v2.y); row2[2] = b2f(v2.z); row2[3] = b2f(v2.w);
            row3[0] = b2f(v3.x); row3[1] = b2f(v3.y); row3[2] = b2f(v3.z); row3[3] = b2f(v3.w);
        } else {
            ushort2 v0 = *(const ushort2*)(H + (size_t)r0 * F + lane * 2);
            ushort2 v1 = *(const ushort2*)(H + (size_t)r1 * F + lane * 2);
            ushort2 v2 = *(const ushort2*)(H + (size_t)r2 * F + lane * 2);
            ushort2 v3 = *(const ushort2*)(H + (size_t)r3 * F + lane * 2);
            row0[0] = b2f(v0.x); row0[1] = b2f(v0.y);
            row1[0] = b2f(v1.x); row1[1] = b2f(v1.y);
            row2[0] = b2f(v2.x); row2[1] = b2f(v2.y);
            row3[0] = b2f(v3.x); row3[1] = b2f(v3.y);
        }
        float e0 = as[r0] + adi; e0 = e0 > 0.f ? e0 : 0.2f * e0;
        float e1 = as[r1] + adi; e1 = e1 > 0.f ? e1 : 0.2f * e1;
        float e2 = as[r2] + adi; e2 = e2 > 0.f ? e2 : 0.2f * e2;
        float e3 = as[r3] + adi; e3 = e3 > 0.f ? e3 : 0.2f * e3;
        float em = fmaxf(fmaxf(e0, e1), fmaxf(e2, e3));
        if (em > m + THR) {                    // wave-uniform (e uniform across lanes)
            float sc = __expf(m - em);         // exp(-inf)=0 handles first iteration
            ssum *= sc;
#pragma unroll
            for (int j = 0; j < V; ++j) acc[j] *= sc;
            m = em;
        }
        float w0 = __expf(e0 - m), w1 = __expf(e1 - m);
        float w2 = __expf(e2 - m), w3 = __expf(e3 - m);
        ssum += (w0 + w1) + (w2 + w3);
#pragma unroll
        for (int j = 0; j < V; ++j)
            acc[j] += (w0 * row0[j] + w1 * row1[j]) + (w2 * row2[j] + w3 * row3[j]);
    }
    for (; k < s1; ++k) {
        int r0 = esrc[k];
        float row0[V];
        if (V == 4) {
            ushort4 v0 = *(const ushort4*)(H + (size_t)r0 * F + lane * 4);
            row0[0] = b2f(v0.x); row0[1] = b2f(v0.y); row0[2] = b2f(v0.z); row0[3] = b2f(v0.w);
        } else {
            ushort2 v0 = *(const ushort2*)(H + (size_t)r0 * F + lane * 2);
            row0[0] = b2f(v0.x); row0[1] = b2f(v0.y);
        }
        float e0 = as[r0] + adi; e0 = e0 > 0.f ? e0 : 0.2f * e0;
        if (e0 > m + THR) {
            float sc = __expf(m - e0);
            ssum *= sc;
#pragma unroll
            for (int j = 0; j < V; ++j) acc[j] *= sc;
            m = e0;
        }
        float w0 = __expf(e0 - m);
        ssum += w0;
#pragma unroll
        for (int j = 0; j < V; ++j) acc[j] += w0 * row0[j];
    }
    float inv = 1.f / ssum;
    float r[V];
#pragma unroll
    for (int j = 0; j < V; ++j) {
        r[j] = acc[j] * inv + bias[lane * V + j];
        if (RELU) r[j] = fmaxf(r[j], 0.f);
    }
    if (V == 4) *(float4*)(out + (size_t)gw * F + lane * 4) = make_float4(r[0], r[1], r[2], r[3]);
    else        *(float2*)(out + (size_t)gw * F + lane * 2) = make_float2(r[0], r[1]);
}

// ---------------- launch ----------------

static inline size_t al256(size_t x) { return (x + 255) & ~(size_t)255; }

extern "C" void kernel_launch(void* const* d_in, const int* in_sizes, int n_in,
                              void* d_out, int out_size, void* d_ws, size_t ws_size,
                              hipStream_t stream) {
    const float* x   = (const float*)d_in[0];
    const int*   ei  = (const int*)d_in[1];
    const float* W1  = (const float*)d_in[2];
    const float* as1 = (const float*)d_in[3];
    const float* ad1 = (const float*)d_in[4];
    const float* b1  = (const float*)d_in[5];
    const float* W2  = (const float*)d_in[6];
    const float* as2 = (const float*)d_in[7];
    const float* ad2 = (const float*)d_in[8];
    const float* b2  = (const float*)d_in[9];

    float* out_x2 = (float*)d_out;                          // [50000,128]
    float* out_h  = (float*)d_out + (size_t)N_NODES * 128;  // [50000,256] fp32

    const size_t NM256 = (size_t)N_NODES * 256 * 2;         // bf16 [50000][256]
    char* base = (char*)d_ws;
    size_t off = 0;
    auto take = [&](size_t bytes) { char* p = base + off; off = al256(off + bytes); return p; };

    ushort* h1b  = (ushort*)take(NM256);            // layer1 GEMM out (bf16); reused as layer2 gb
    ushort* w1th = (ushort*)take(256 * 256 * 2);
    ushort* w1tl = (ushort*)take(256 * 256 * 2);
    ushort* w2th = (ushort*)take(256 * 128 * 2);
    ushort* w2tl = (ushort*)take(256 * 128 * 2);
    float*  asb  = (float*)take(N_NODES * 4);
    float*  adb  = (float*)take(N_NODES * 4);
    int*    deg  = (int*)take(N_NODES * 4);
    int*    offs = (int*)take((N_NODES + 4) * 4);
    int*    curs = (int*)take(N_NODES * 4);
    int*    bsum = (int*)take(1024);
    int*    esrc = (int*)take((size_t)ETOT * 4);
    (void)ws_size;

    hipMemsetAsync(deg, 0, N_NODES * sizeof(int), stream);

    int nbE = (ETOT + 255) / 256;
    int nbN = (N_NODES + 255) / 256;
    int nbW = (N_NODES * 64 + 255) / 256;       // one wave per node

    // CSR by dst
    k_deg<<<nbE, 256, 0, stream>>>(ei, deg);
    k_scan1<<<nbN, 256, 0, stream>>>(deg, offs, bsum);
    k_scan2<<<1, 256, 0, stream>>>(bsum, nbN);
    k_scan3<<<nbN, 256, 0, stream>>>(offs, bsum);
    k_copy<<<nbN, 256, 0, stream>>>(offs, curs);
    k_scatter<<<nbE, 256, 0, stream>>>(ei, curs, esrc);

    // weight transpose+split (tiny)
    k_splitT<<<(256 * 256 + 255) / 256, 256, 0, stream>>>(W1, w1th, w1tl, 256, 256);
    k_splitT<<<(256 * 128 + 255) / 256, 256, 0, stream>>>(W2, w2th, w2tl, 256, 128);

    dim3 g1((N_NODES + 127) / 128, 2), g2((N_NODES + 127) / 128, 1);

    // ---- layer 1
    k_gemm_mfma<<<g1, 256, 0, stream>>>(x, w1th, w1tl, h1b, N_NODES, 256, 256);
    k_alpha<256><<<nbW, 256, 0, stream>>>(h1b, as1, ad1, asb, adb);
    k_aggf<256, true><<<nbW, 256, 0, stream>>>(offs, esrc, asb, adb, h1b, b1, out_h);

    // ---- layer 2 (A = out_h fp32 read directly; gb reuses h1b)
    ushort* gb = h1b;
    k_gemm_mfma<<<g2, 256, 0, stream>>>(out_h, w2th, w2tl, gb, N_NODES, 128, 256);
    k_alpha<128><<<nbW, 256, 0, stream>>>(gb, as2, ad2, asb, adb);
    k_aggf<128, false><<<nbW, 256, 0, stream>>>(offs, esrc, asb, adb, gb, b2, out_x2);
}